// Round 7
// baseline (149.943 us; speedup 1.0000x reference)
//
#include <hip/hip_runtime.h>

#define TOKENS 65536
#define DIM 64
#define NCODE 1024
// fp16-screen margin (unscaled). Screen error bound: ~192 f32 roundings x
// ulp(3e5 scaled)/2^21 ~ 2.9e-6 worst-case; 1e-5 gives 3.4x headroom.
#define MARGIN 1e-5f
#define MARGINS (MARGIN * 2097152.0f)   // scaled-domain threshold (x 2^21)
#define FLAG_CAP 8192
#define TPG 16   // tokens per exact-pass group

#define OUT_IDX_OFF ((size_t)TOKENS * DIM)          // 4194304
#define OUT_LOSS_OFF (OUT_IDX_OFF + TOKENS)         // 4259840

// ws layout (bytes):
#define WS_LOSS   0        // double
#define WS_FLAGC  8        // uint
#define WS_DONEA  12       // uint (global finisher counter)
#define WS_DGRP   16       // uint[512] per-group done counters -> 2064
#define WS_BNORM  2064     // f32[1024] -> 6160 (unscaled, exact pass)
#define WS_BNS    6160     // f32[1024] -> 10256 (x2^21, screen)
#define WS_CHI    10256    // ushort[65536] -> 141328 (fp16 hi of -8192*c)
#define WS_CLO    141328   // ushort[65536] -> 272400 (fp16 lo)
#define WS_PACKED 272400   // u64[8192] -> 337936 (per-flagged argmin)
#define WS_FLAGS  337936   // int[8192] -> 370704

typedef __attribute__((ext_vector_type(8))) short short8;
typedef __attribute__((ext_vector_type(8))) _Float16 half8;
typedef __attribute__((ext_vector_type(4))) float f32x4;

static __device__ __forceinline__ half8 as_h8(short8 v) {
    return __builtin_bit_cast(half8, v);
}

// async global->LDS DMA, 16B per lane. Dest must be wave-uniform base;
// HW writes base + lane*16 (linear) — exactly our verified staging layout.
static __device__ __forceinline__ void dma16(const void* g, void* l) {
    __builtin_amdgcn_global_load_lds(
        (const __attribute__((address_space(1))) unsigned int*)g,
        (__attribute__((address_space(3))) unsigned int*)l, 16, 0, 0);
}

// ---------------------------------------------------------------------------
// numpy-bitwise f32 sum-of-squares — VERIFIED absmax=0 (round 2). Do not touch.
// ---------------------------------------------------------------------------
__device__ __forceinline__ float np_sumsq64(const float* __restrict__ x) {
#pragma clang fp contract(off)
    float r[8];
#pragma unroll
    for (int j = 0; j < 8; ++j) r[j] = x[j] * x[j];
#pragma unroll
    for (int i = 8; i < 64; i += 8) {
#pragma unroll
        for (int j = 0; j < 8; ++j) {
            float sq = x[i + j] * x[i + j];
            r[j] = r[j] + sq;
        }
    }
    return ((r[0] + r[1]) + (r[2] + r[3])) + ((r[4] + r[5]) + (r[6] + r[7]));
}

// ---------------------------------------------------------------------------
// Prep v2 (r13, UNCHANGED): codebook -> fp16 hi/lo A-frags of (-2*4096*C)
// + bnorm (unscaled, exact pass) + bns (= bnorm * 2^21, screen).
// ---------------------------------------------------------------------------
__global__ __launch_bounds__(256) void vq_prep(
    const float* __restrict__ cb, unsigned short* __restrict__ chi,
    unsigned short* __restrict__ clo, float* __restrict__ bnorm,
    float* __restrict__ bns,
    unsigned int* __restrict__ ctrl /* 516 u32 at ws+0 */) {
    int tid = blockIdx.x * 256 + threadIdx.x;   // 0..65535
    if (tid < 516) ctrl[tid] = 0u;
    int j = tid & 7;
    int L = (tid >> 3) & 63;
    int cs = tid >> 9;          // 0..127
    int s = cs & 1, c = cs >> 1;
    int code = c * 16 + (L & 15);
    int d = s * 32 + (L >> 4) * 8 + j;
    float v = -8192.0f * cb[(size_t)code * DIM + d];   // -2c * 4096 (exact)
    _Float16 h = (_Float16)v;                          // RN f32->f16
    float hf = (float)h;
    float lo;
    {
#pragma clang fp contract(off)
        lo = v - hf;                                   // exact in f32
    }
    _Float16 l = (_Float16)lo;
    chi[tid] = __builtin_bit_cast(unsigned short, h);
    clo[tid] = __builtin_bit_cast(unsigned short, l);

    if (tid < NCODE) {
        float bn = np_sumsq64(cb + (size_t)tid * DIM);
        bnorm[tid] = bn;
        bns[tid] = bn * 2097152.0f;                    // x 2^21 (exact)
    }
}

__device__ __forceinline__ void top2_merge(float& a1, float& a2, int& ai,
                                           float b1, float b2, int bi) {
    float n1 = fminf(a1, b1);
    float n2 = fminf(fmaxf(a1, b1), fminf(a2, b2));
    ai = (b1 < a1) ? bi : ai;   // ties keep a (exact ties get flagged anyway)
    a1 = n1; a2 = n2;
}

// ---------------------------------------------------------------------------
// Fast screen, v12 (r16 resubmit; r6 bench was an infra failure, not a
// kernel verdict): EXACT r3/v9 structure (best: 51.5us) with ONE change —
// staging via __builtin_amdgcn_global_load_lds (16B DMA) instead of
// global->reg->ds_write. r4/r5 showed occupancy and L2 stream are not
// binding past ~25%; r3's remaining serial segment was the per-group
// vmcnt-wait -> 4x ds_write_b128 -> barrier tail, plus ~5us/CU of staging
// writes on the LDS pipe. DMA removes both: loads land during compute,
// barrier's vmcnt(0) drain is already satisfied. Lane l of wave w writes
// sh[w*64+l] (contiguous 16B) — identical LDS bytes/layout to verified r3
// -> every ds_read, MFMA, flag decision bitwise-identical. Grid 1024x256,
// 4 blocks/CU. Epilogue/exact pass untouched.
// ---------------------------------------------------------------------------
__global__ __launch_bounds__(256, 4) void vq_fast(
    const float* __restrict__ z, const float* __restrict__ cb,
    const unsigned short* __restrict__ cfrag_hi,
    const unsigned short* __restrict__ cfrag_lo,
    const float* __restrict__ bnorm_s, float* __restrict__ out,
    unsigned int* __restrict__ flag_count, int* __restrict__ flag_list,
    unsigned long long* __restrict__ packed_min,
    double* __restrict__ loss_sum, unsigned int flag_cap) {
    __shared__ short8 sh_hi[2][512];   // [buf][(cc*2+step)*64 + lane], 8KB each
    __shared__ short8 sh_lo[2][512];
    __shared__ float bn_lds[NCODE];
    __shared__ int s_best[64];
    __shared__ int s_flag[64];

    const int tid = threadIdx.x;
    const int lane = tid & 63;
    const int w = tid >> 6;
    const int t0 = blockIdx.x * 64;
    const int tw = t0 + w * 16;              // this wave's 16 tokens
    const int col = lane & 15;
    const int quad = lane >> 4;

    // stage scaled bnorm into LDS (4 KB)
    ((float4*)bn_lds)[tid] = ((const float4*)bnorm_s)[tid];

    // token B-fragments (fp16 hi/lo of z*512), 2 K-steps, in registers
    half8 zhi[2], zlo[2];
#pragma unroll
    for (int s = 0; s < 2; ++s) {
        const float* zp = z + (size_t)(tw + col) * DIM + s * 32 + quad * 8;
        float4 f0 = ((const float4*)zp)[0];
        float4 f1 = ((const float4*)zp)[1];
        float f[8] = {f0.x, f0.y, f0.z, f0.w, f1.x, f1.y, f1.z, f1.w};
        half8 hh8, ll8;
#pragma unroll
        for (int j = 0; j < 8; ++j) {
            float sv = f[j] * 512.0f;        // exact pow2 scale
            _Float16 hh = (_Float16)sv;      // RN
            float hf = (float)hh;
            float lo;
            {
#pragma clang fp contract(off)
                lo = sv - hf;                // exact in f32
            }
            hh8[j] = hh;
            ll8[j] = (_Float16)lo;
        }
        zhi[s] = hh8; zlo[s] = ll8;
    }

    const short8* CH = (const short8*)cfrag_hi;   // 4096 short8 (64 chunks)
    const short8* CL = (const short8*)cfrag_lo;

    // stage group 0 via DMA (same bytes/offsets as verified reg-staging)
    {
        dma16(CH + (w * 64 + lane),       &sh_hi[0][w * 64]);
        dma16(CH + (256 + w * 64 + lane), &sh_hi[0][256 + w * 64]);
        dma16(CL + (w * 64 + lane),       &sh_lo[0][w * 64]);
        dma16(CL + (256 + w * 64 + lane), &sh_lo[0][256 + w * 64]);
    }
    __syncthreads();

    float m1 = 3.0e38f, m2 = 3.0e38f;
    int bi = 0;
    const int koff = quad * 4;

    for (int g = 0; g < 16; ++g) {
        const int buf = g & 1;
        if (g < 15) {               // issue next group's DMA first
            const int base = (g + 1) * 512;
            short8* dh = &sh_hi[buf ^ 1][0];
            short8* dl = &sh_lo[buf ^ 1][0];
            dma16(CH + (base + w * 64 + lane),       dh + w * 64);
            dma16(CH + (base + 256 + w * 64 + lane), dh + 256 + w * 64);
            dma16(CL + (base + w * 64 + lane),       dl + w * 64);
            dma16(CL + (base + 256 + w * 64 + lane), dl + 256 + w * 64);
        }
#pragma unroll
        for (int cc = 0; cc < 4; ++cc) {
            const int c = g * 4 + cc;
            short8 ch0 = sh_hi[buf][(cc * 2 + 0) * 64 + lane];
            short8 ch1 = sh_hi[buf][(cc * 2 + 1) * 64 + lane];
            short8 cl0 = sh_lo[buf][(cc * 2 + 0) * 64 + lane];
            short8 cl1 = sh_lo[buf][(cc * 2 + 1) * 64 + lane];
            const int cbase = c * 16 + koff;
            const f32x4 bn = *(const f32x4*)&bn_lds[cbase];
            f32x4 acc = bn;
            acc = __builtin_amdgcn_mfma_f32_16x16x32_f16(as_h8(ch0), zhi[0], acc, 0, 0, 0);
            acc = __builtin_amdgcn_mfma_f32_16x16x32_f16(as_h8(cl0), zhi[0], acc, 0, 0, 0);
            acc = __builtin_amdgcn_mfma_f32_16x16x32_f16(as_h8(ch0), zlo[0], acc, 0, 0, 0);
            acc = __builtin_amdgcn_mfma_f32_16x16x32_f16(as_h8(ch1), zhi[1], acc, 0, 0, 0);
            acc = __builtin_amdgcn_mfma_f32_16x16x32_f16(as_h8(cl1), zhi[1], acc, 0, 0, 0);
            acc = __builtin_amdgcn_mfma_f32_16x16x32_f16(as_h8(ch1), zlo[1], acc, 0, 0, 0);
#pragma unroll
            for (int i = 0; i < 4; ++i) {
                float u = acc[i];
                float om1 = m1;
                bool lt = u < om1;
                float fm = fminf(m2, u);
                m2 = lt ? om1 : fm;
                m1 = lt ? u : om1;
                bi = lt ? (cbase + i) : bi;
            }
        }
        if (g < 15) __syncthreads();
    }

    // in-wave quad merge (lanes l, l^16, l^32, l^48 share a token column)
    {
        float a1 = m1, a2 = m2;
        int ai = bi;
        {
            float o1 = __shfl_xor(a1, 16); float o2 = __shfl_xor(a2, 16);
            int oi = __shfl_xor(ai, 16);
            top2_merge(a1, a2, ai, o1, o2, oi);
        }
        {
            float o1 = __shfl_xor(a1, 32); float o2 = __shfl_xor(a2, 32);
            int oi = __shfl_xor(ai, 32);
            top2_merge(a1, a2, ai, o1, o2, oi);
        }
        if (quad == 0) {
            const int slot = w * 16 + col;
            int fl = (a2 - a1) < MARGINS;
            if (fl) {
                unsigned int pos = atomicAdd(flag_count, 1u);
                if (pos >= flag_cap) fl = 0;
                else {
                    flag_list[pos] = t0 + slot;
                    packed_min[pos] = ~0ull;   // lazy init (no memset node)
                }
            }
            s_best[slot] = ai;
            s_flag[slot] = fl;
        }
    }
    __syncthreads();

    // epilogue: 2 threads per token, 32 floats each (r6-verified partial
    // structure); flagged deferred.
    const int et = tid >> 1, h = tid & 1;
    float loss_t = 0.0f;
    if (et < 64 && !s_flag[et]) {
        const int B = s_best[et];
        const float4* cq  = (const float4*)(cb + (size_t)B * DIM + h * 32);
        const float4* zq4 = (const float4*)(z + (size_t)(t0 + et) * DIM + h * 32);
        float4* o4 = (float4*)(out + (size_t)(t0 + et) * DIM + h * 32);
#pragma unroll
        for (int jj = 0; jj < 8; ++jj) {
#pragma clang fp contract(off)
            float4 cc = cq[jj];
            float4 zz = zq4[jj];
            float d0 = cc.x - zz.x, d1 = cc.y - zz.y;
            float d2 = cc.z - zz.z, d3 = cc.w - zz.w;
            float4 o;
            o.x = zz.x + d0; o.y = zz.y + d1;
            o.z = zz.z + d2; o.w = zz.w + d3;
            o4[jj] = o;
            loss_t = __fmaf_rn(d0, d0, loss_t);
            loss_t = __fmaf_rn(d1, d1, loss_t);
            loss_t = __fmaf_rn(d2, d2, loss_t);
            loss_t = __fmaf_rn(d3, d3, loss_t);
        }
        if (h == 0) out[OUT_IDX_OFF + t0 + et] = (float)B;
    }
#pragma unroll
    for (int off = 32; off > 0; off >>= 1)
        loss_t += __shfl_down(loss_t, off);
    if (lane == 0 && w < 2) atomicAdd(loss_sum, (double)loss_t);
}

__device__ __forceinline__ unsigned long long shfl_down_u64(unsigned long long v, int off) {
    unsigned int lo = (unsigned int)v, hi = (unsigned int)(v >> 32);
    lo = __shfl_down(lo, off);
    hi = __shfl_down(hi, off);
    return ((unsigned long long)hi << 32) | lo;
}

// ---------------------------------------------------------------------------
// Exact numpy-bitwise pass, v4: UNCHANGED (verified rounds 6-10). Uses
// unscaled bnorm; arithmetic bitwise-identical.
// ---------------------------------------------------------------------------
__global__ __launch_bounds__(256) void vq_exact_min(
    const float* __restrict__ z, const float* __restrict__ cb,
    const float* __restrict__ bnorm,
    const unsigned int* __restrict__ flag_count,
    const int* __restrict__ flag_list,
    unsigned long long* __restrict__ packed_min,
    unsigned int* __restrict__ done_grp, unsigned int* __restrict__ done_all,
    float* __restrict__ out, double* __restrict__ loss_sum,
    unsigned int flag_cap) {
    __shared__ float zsh[TPG * 68];
    __shared__ float szs[TPG];
    __shared__ unsigned int s_old;

    const int tid = threadIdx.x;
    const int w = tid >> 6;
    const int lane = tid & 63;
    unsigned int count = *flag_count;
    if (count > flag_cap) count = flag_cap;
    const unsigned int ngroups = (count + TPG - 1) / TPG;   // <= 512

    if (count == 0) {   // no flagged tokens: block 0 writes the loss
        if (blockIdx.x == 0 && tid == 0) {
            double L = atomicAdd(loss_sum, 0.0);
            out[OUT_LOSS_OFF] = (float)(2.0 * L / (double)((size_t)TOKENS * DIM));
        }
        return;
    }

    const int q = blockIdx.x & 3;
    const unsigned int g = blockIdx.x >> 2;          // 0..511
    if (g >= ngroups) return;

    const int k = q * 256 + w * 64 + lane;           // this lane's code

    float row[DIM];
    {
        const float4* c4 = (const float4*)(cb + (size_t)k * DIM);
#pragma unroll
        for (int j = 0; j < 16; ++j) {
            float4 v = c4[j];
            row[4 * j + 0] = v.x; row[4 * j + 1] = v.y;
            row[4 * j + 2] = v.z; row[4 * j + 3] = v.w;
        }
    }
    const float bnk = bnorm[k];

    {
        const int i = tid >> 2, part = tid & 3;
        if (i < TPG) {
            const unsigned int li = g * TPG + i;
            if (li < count) {
                const int t = flag_list[li];
                const float4* zp = (const float4*)(z + (size_t)t * DIM + part * 16);
                float4* dst = (float4*)(zsh + i * 68 + part * 16);
#pragma unroll
                for (int e = 0; e < 4; ++e) dst[e] = zp[e];
            }
        }
    }
    __syncthreads();
    if (tid < TPG) szs[tid] = np_sumsq64(zsh + tid * 68);
    __syncthreads();

    for (int tt = 0; tt < TPG; ++tt) {
        const unsigned int li = g * TPG + tt;
        const float* zp = zsh + tt * 68;             // wave-uniform -> broadcast
        float l16[16];
#pragma unroll
        for (int g2 = 0; g2 < 4; ++g2) {
            float4 v0 = ((const float4*)(zp + 4 * g2))[0];
            float4 v1 = ((const float4*)(zp + 16 + 4 * g2))[0];
            float4 v2 = ((const float4*)(zp + 32 + 4 * g2))[0];
            float4 v3 = ((const float4*)(zp + 48 + 4 * g2))[0];
            float a0[4] = {v0.x, v0.y, v0.z, v0.w};
            float a1[4] = {v1.x, v1.y, v1.z, v1.w};
            float a2[4] = {v2.x, v2.y, v2.z, v2.w};
            float a3[4] = {v3.x, v3.y, v3.z, v3.w};
#pragma unroll
            for (int e = 0; e < 4; ++e) {
#pragma clang fp contract(off)
                int jj = 4 * g2 + e;
                float acc = a3[e] * row[48 + jj];
                acc = __fmaf_rn(a2[e], row[32 + jj], acc);
                acc = __fmaf_rn(a1[e], row[16 + jj], acc);
                acc = __fmaf_rn(a0[e], row[jj],      acc);
                l16[jj] = acc;
            }
        }
        float e_np;
        {
#pragma clang fp contract(off)
#pragma unroll
            for (int jj = 0; jj < 8; ++jj) l16[jj] = l16[jj] + l16[jj + 8];
#pragma unroll
            for (int jj = 0; jj < 4; ++jj) l16[jj] = l16[jj] + l16[jj + 4];
            l16[0] = l16[0] + l16[2];
            l16[1] = l16[1] + l16[3];
            e_np = l16[0] + l16[1];
        }
        float dd;
        {
#pragma clang fp contract(off)
            float t1 = szs[tt] + bnk;
            float mm = 2.0f * e_np;
            dd = t1 - mm;
        }
        unsigned long long pk =
            ((unsigned long long)__float_as_uint(dd) << 10) | (unsigned int)k;
#pragma unroll
        for (int off = 32; off > 0; off >>= 1) {
            unsigned long long o = shfl_down_u64(pk, off);
            pk = (o < pk) ? o : pk;
        }
        if (lane == 0 && li < count)
            atomicMin(&packed_min[li], pk);
    }

    // ---- fused finish: 4th quarter-block of this group writes outputs ----
    __threadfence();
    __syncthreads();
    if (tid == 0) s_old = atomicAdd(&done_grp[g], 1u);
    __syncthreads();
    if (s_old != 3u) return;
    __threadfence();

    for (int tt = w * (TPG / 4); tt < (w + 1) * (TPG / 4); ++tt) {
        const unsigned int li = g * TPG + tt;
        if (li >= count) break;
        const int t = flag_list[li];
        const unsigned long long pk = atomicAdd(&packed_min[li], 0ull);  // coherent
        const int best = (int)(pk & 1023ull);
        const float zl = zsh[tt * 68 + lane];
        const float zq = cb[(size_t)best * DIM + lane];
        float d, o;
        {
#pragma clang fp contract(off)
            d = zq - zl;
            o = zl + d;
        }
        out[(size_t)t * DIM + lane] = o;
        float l2 = d * d;
#pragma unroll
        for (int off = 32; off > 0; off >>= 1)
            l2 += __shfl_down(l2, off);
        if (lane == 0) {
            out[OUT_IDX_OFF + t] = (float)best;
            atomicAdd(loss_sum, (double)l2);
        }
    }

    __threadfence();
    __syncthreads();
    if (tid == 0) {
        unsigned int old = atomicAdd(done_all, 1u);
        if (old == ngroups - 1) {
            double L = atomicAdd(loss_sum, 0.0);   // coherent read-through
            out[OUT_LOSS_OFF] = (float)(2.0 * L / (double)((size_t)TOKENS * DIM));
        }
    }
}

extern "C" void kernel_launch(void* const* d_in, const int* in_sizes, int n_in,
                              void* d_out, int out_size, void* d_ws, size_t ws_size,
                              hipStream_t stream) {
    const float* z  = (const float*)d_in[0];   // [8,8192,64] f32
    const float* cb = (const float*)d_in[1];   // [1024,64] f32
    float* out = (float*)d_out;

    char* ws = (char*)d_ws;
    double* loss_sum = (double*)(ws + WS_LOSS);
    unsigned int* flag_count = (unsigned int*)(ws + WS_FLAGC);
    unsigned int* done_all = (unsigned int*)(ws + WS_DONEA);
    unsigned int* done_grp = (unsigned int*)(ws + WS_DGRP);
    float* bnorm = (float*)(ws + WS_BNORM);
    float* bns = (float*)(ws + WS_BNS);
    unsigned short* chi = (unsigned short*)(ws + WS_CHI);
    unsigned short* clo = (unsigned short*)(ws + WS_CLO);
    unsigned long long* packed = (unsigned long long*)(ws + WS_PACKED);
    int* flag_list = (int*)(ws + WS_FLAGS);

    unsigned int cap = 0;
    if (ws_size > WS_FLAGS + 4) {
        size_t c = (ws_size - WS_FLAGS) / 4;
        cap = (c > FLAG_CAP) ? FLAG_CAP : (unsigned int)c;
    }

    vq_prep<<<dim3(256), dim3(256), 0, stream>>>(
        cb, chi, clo, bnorm, bns, (unsigned int*)ws);
    vq_fast<<<dim3(TOKENS / 64), dim3(256), 0, stream>>>(
        z, cb, chi, clo, bns, out, flag_count, flag_list, packed, loss_sum, cap);
    vq_exact_min<<<dim3(2048), dim3(256), 0, stream>>>(
        z, cb, bnorm, flag_count, flag_list, packed, done_grp, done_all,
        out, loss_sum, cap);
}

// Round 8
// 138.381 us; speedup vs baseline: 1.0836x; 1.0836x over previous
//
#include <hip/hip_runtime.h>

#define TOKENS 65536
#define DIM 64
#define NCODE 1024
// fp16-screen margin (unscaled). Screen error bound: ~192 f32 roundings x
// ulp(3e5 scaled)/2^21 ~ 2.9e-6 worst-case; 1e-5 gives 3.4x headroom.
#define MARGIN 1e-5f
#define MARGINS (MARGIN * 2097152.0f)   // scaled-domain threshold (x 2^21)
#define FLAG_CAP 4096   // r8: TPG=8 x 512 groups (done_grp capacity). actual ~110
#define TPG 8    // r8: 16 -> 8. Exact pass is serial-chain bound per group;
                 // halving TPG halves the chain, doubles active blocks.

#define OUT_IDX_OFF ((size_t)TOKENS * DIM)          // 4194304
#define OUT_LOSS_OFF (OUT_IDX_OFF + TOKENS)         // 4259840

// ws layout (bytes):
#define WS_LOSS   0        // double
#define WS_FLAGC  8        // uint
#define WS_DONEA  12       // uint (global finisher counter)
#define WS_DGRP   16       // uint[512] per-group done counters -> 2064
#define WS_BNORM  2064     // f32[1024] -> 6160 (unscaled, exact pass)
#define WS_BNS    6160     // f32[1024] -> 10256 (x2^21, screen)
#define WS_CHI    10256    // ushort[65536] -> 141328 (fp16 hi of -8192*c)
#define WS_CLO    141328   // ushort[65536] -> 272400 (fp16 lo)
#define WS_PACKED 272400   // u64[8192] -> 337936 (per-flagged argmin)
#define WS_FLAGS  337936   // int[8192] -> 370704

typedef __attribute__((ext_vector_type(8))) short short8;
typedef __attribute__((ext_vector_type(8))) _Float16 half8;
typedef __attribute__((ext_vector_type(4))) float f32x4;

static __device__ __forceinline__ half8 as_h8(short8 v) {
    return __builtin_bit_cast(half8, v);
}

// ---------------------------------------------------------------------------
// numpy-bitwise f32 sum-of-squares — VERIFIED absmax=0 (round 2). Do not touch.
// ---------------------------------------------------------------------------
__device__ __forceinline__ float np_sumsq64(const float* __restrict__ x) {
#pragma clang fp contract(off)
    float r[8];
#pragma unroll
    for (int j = 0; j < 8; ++j) r[j] = x[j] * x[j];
#pragma unroll
    for (int i = 8; i < 64; i += 8) {
#pragma unroll
        for (int j = 0; j < 8; ++j) {
            float sq = x[i + j] * x[i + j];
            r[j] = r[j] + sq;
        }
    }
    return ((r[0] + r[1]) + (r[2] + r[3])) + ((r[4] + r[5]) + (r[6] + r[7]));
}

// ---------------------------------------------------------------------------
// Prep v2 (r13, UNCHANGED): codebook -> fp16 hi/lo A-frags of (-2*4096*C)
// + bnorm (unscaled, exact pass) + bns (= bnorm * 2^21, screen).
// ---------------------------------------------------------------------------
__global__ __launch_bounds__(256) void vq_prep(
    const float* __restrict__ cb, unsigned short* __restrict__ chi,
    unsigned short* __restrict__ clo, float* __restrict__ bnorm,
    float* __restrict__ bns,
    unsigned int* __restrict__ ctrl /* 516 u32 at ws+0 */) {
    int tid = blockIdx.x * 256 + threadIdx.x;   // 0..65535
    if (tid < 516) ctrl[tid] = 0u;
    int j = tid & 7;
    int L = (tid >> 3) & 63;
    int cs = tid >> 9;          // 0..127
    int s = cs & 1, c = cs >> 1;
    int code = c * 16 + (L & 15);
    int d = s * 32 + (L >> 4) * 8 + j;
    float v = -8192.0f * cb[(size_t)code * DIM + d];   // -2c * 4096 (exact)
    _Float16 h = (_Float16)v;                          // RN f32->f16
    float hf = (float)h;
    float lo;
    {
#pragma clang fp contract(off)
        lo = v - hf;                                   // exact in f32
    }
    _Float16 l = (_Float16)lo;
    chi[tid] = __builtin_bit_cast(unsigned short, h);
    clo[tid] = __builtin_bit_cast(unsigned short, l);

    if (tid < NCODE) {
        float bn = np_sumsq64(cb + (size_t)tid * DIM);
        bnorm[tid] = bn;
        bns[tid] = bn * 2097152.0f;                    // x 2^21 (exact)
    }
}

__device__ __forceinline__ void top2_merge(float& a1, float& a2, int& ai,
                                           float b1, float b2, int bi) {
    float n1 = fminf(a1, b1);
    float n2 = fminf(fmaxf(a1, b1), fminf(a2, b2));
    ai = (b1 < a1) ? bi : ai;   // ties keep a (exact ties get flagged anyway)
    a1 = n1; a2 = n2;
}

// ---------------------------------------------------------------------------
// Fast screen, v9 (r13/r3 VERBATIM — best verified: 51.5us). r4 (code-split),
// r5 (wide block), r7 (global_load_lds DMA) all regressed; r7 post-mortem:
// DMA's LDS writes land during compute and contend with ds_reads on the LDS
// pipe, vs reg-staging's end-of-group burst that overlaps other blocks'
// compute. Do not restructure without new counter evidence.
// ---------------------------------------------------------------------------
__global__ __launch_bounds__(256, 4) void vq_fast(
    const float* __restrict__ z, const float* __restrict__ cb,
    const unsigned short* __restrict__ cfrag_hi,
    const unsigned short* __restrict__ cfrag_lo,
    const float* __restrict__ bnorm_s, float* __restrict__ out,
    unsigned int* __restrict__ flag_count, int* __restrict__ flag_list,
    unsigned long long* __restrict__ packed_min,
    double* __restrict__ loss_sum, unsigned int flag_cap) {
    __shared__ short8 sh_hi[2][512];   // [buf][(cc*2+step)*64 + lane], 8KB each
    __shared__ short8 sh_lo[2][512];
    __shared__ float bn_lds[NCODE];
    __shared__ int s_best[64];
    __shared__ int s_flag[64];

    const int tid = threadIdx.x;
    const int lane = tid & 63;
    const int w = tid >> 6;
    const int t0 = blockIdx.x * 64;
    const int tw = t0 + w * 16;              // this wave's 16 tokens
    const int col = lane & 15;
    const int quad = lane >> 4;

    // stage scaled bnorm into LDS (4 KB)
    ((float4*)bn_lds)[tid] = ((const float4*)bnorm_s)[tid];

    // token B-fragments (fp16 hi/lo of z*512), 2 K-steps, in registers
    half8 zhi[2], zlo[2];
#pragma unroll
    for (int s = 0; s < 2; ++s) {
        const float* zp = z + (size_t)(tw + col) * DIM + s * 32 + quad * 8;
        float4 f0 = ((const float4*)zp)[0];
        float4 f1 = ((const float4*)zp)[1];
        float f[8] = {f0.x, f0.y, f0.z, f0.w, f1.x, f1.y, f1.z, f1.w};
        half8 hh8, ll8;
#pragma unroll
        for (int j = 0; j < 8; ++j) {
            float sv = f[j] * 512.0f;        // exact pow2 scale
            _Float16 hh = (_Float16)sv;      // RN
            float hf = (float)hh;
            float lo;
            {
#pragma clang fp contract(off)
                lo = sv - hf;                // exact in f32
            }
            hh8[j] = hh;
            ll8[j] = (_Float16)lo;
        }
        zhi[s] = hh8; zlo[s] = ll8;
    }

    const short8* CH = (const short8*)cfrag_hi;   // 4096 short8 (64 chunks)
    const short8* CL = (const short8*)cfrag_lo;

    // stage group 0 (4 chunks = 512 short8 per array; 2 per thread per array)
    {
        short8 a0 = CH[tid], a1 = CH[tid + 256];
        short8 b0 = CL[tid], b1 = CL[tid + 256];
        sh_hi[0][tid] = a0; sh_hi[0][tid + 256] = a1;
        sh_lo[0][tid] = b0; sh_lo[0][tid + 256] = b1;
    }
    __syncthreads();

    float m1 = 3.0e38f, m2 = 3.0e38f;
    int bi = 0;
    const int koff = quad * 4;

    for (int g = 0; g < 16; ++g) {
        const int buf = g & 1;
        short8 a0, a1, b0, b1;
        if (g < 15) {               // issue next group's loads first
            const int base = (g + 1) * 512 + tid;
            a0 = CH[base]; a1 = CH[base + 256];
            b0 = CL[base]; b1 = CL[base + 256];
        }
#pragma unroll
        for (int cc = 0; cc < 4; ++cc) {
            const int c = g * 4 + cc;
            short8 ch0 = sh_hi[buf][(cc * 2 + 0) * 64 + lane];
            short8 ch1 = sh_hi[buf][(cc * 2 + 1) * 64 + lane];
            short8 cl0 = sh_lo[buf][(cc * 2 + 0) * 64 + lane];
            short8 cl1 = sh_lo[buf][(cc * 2 + 1) * 64 + lane];
            const int cbase = c * 16 + koff;
            const f32x4 bn = *(const f32x4*)&bn_lds[cbase];
            f32x4 acc = bn;
            acc = __builtin_amdgcn_mfma_f32_16x16x32_f16(as_h8(ch0), zhi[0], acc, 0, 0, 0);
            acc = __builtin_amdgcn_mfma_f32_16x16x32_f16(as_h8(cl0), zhi[0], acc, 0, 0, 0);
            acc = __builtin_amdgcn_mfma_f32_16x16x32_f16(as_h8(ch0), zlo[0], acc, 0, 0, 0);
            acc = __builtin_amdgcn_mfma_f32_16x16x32_f16(as_h8(ch1), zhi[1], acc, 0, 0, 0);
            acc = __builtin_amdgcn_mfma_f32_16x16x32_f16(as_h8(cl1), zhi[1], acc, 0, 0, 0);
            acc = __builtin_amdgcn_mfma_f32_16x16x32_f16(as_h8(ch1), zlo[1], acc, 0, 0, 0);
#pragma unroll
            for (int i = 0; i < 4; ++i) {
                float u = acc[i];
                float om1 = m1;
                bool lt = u < om1;
                float fm = fminf(m2, u);
                m2 = lt ? om1 : fm;
                m1 = lt ? u : om1;
                bi = lt ? (cbase + i) : bi;
            }
        }
        if (g < 15) {
            sh_hi[buf ^ 1][tid] = a0; sh_hi[buf ^ 1][tid + 256] = a1;
            sh_lo[buf ^ 1][tid] = b0; sh_lo[buf ^ 1][tid + 256] = b1;
            __syncthreads();
        }
    }

    // in-wave quad merge (lanes l, l^16, l^32, l^48 share a token column)
    {
        float a1 = m1, a2 = m2;
        int ai = bi;
        {
            float o1 = __shfl_xor(a1, 16); float o2 = __shfl_xor(a2, 16);
            int oi = __shfl_xor(ai, 16);
            top2_merge(a1, a2, ai, o1, o2, oi);
        }
        {
            float o1 = __shfl_xor(a1, 32); float o2 = __shfl_xor(a2, 32);
            int oi = __shfl_xor(ai, 32);
            top2_merge(a1, a2, ai, o1, o2, oi);
        }
        if (quad == 0) {
            const int slot = w * 16 + col;
            int fl = (a2 - a1) < MARGINS;
            if (fl) {
                unsigned int pos = atomicAdd(flag_count, 1u);
                if (pos >= flag_cap) fl = 0;
                else {
                    flag_list[pos] = t0 + slot;
                    packed_min[pos] = ~0ull;   // lazy init (no memset node)
                }
            }
            s_best[slot] = ai;
            s_flag[slot] = fl;
        }
    }
    __syncthreads();

    // epilogue: 2 threads per token, 32 floats each (r6-verified partial
    // structure); flagged deferred.
    const int et = tid >> 1, h = tid & 1;
    float loss_t = 0.0f;
    if (et < 64 && !s_flag[et]) {
        const int B = s_best[et];
        const float4* cq  = (const float4*)(cb + (size_t)B * DIM + h * 32);
        const float4* zq4 = (const float4*)(z + (size_t)(t0 + et) * DIM + h * 32);
        float4* o4 = (float4*)(out + (size_t)(t0 + et) * DIM + h * 32);
#pragma unroll
        for (int jj = 0; jj < 8; ++jj) {
#pragma clang fp contract(off)
            float4 cc = cq[jj];
            float4 zz = zq4[jj];
            float d0 = cc.x - zz.x, d1 = cc.y - zz.y;
            float d2 = cc.z - zz.z, d3 = cc.w - zz.w;
            float4 o;
            o.x = zz.x + d0; o.y = zz.y + d1;
            o.z = zz.z + d2; o.w = zz.w + d3;
            o4[jj] = o;
            loss_t = __fmaf_rn(d0, d0, loss_t);
            loss_t = __fmaf_rn(d1, d1, loss_t);
            loss_t = __fmaf_rn(d2, d2, loss_t);
            loss_t = __fmaf_rn(d3, d3, loss_t);
        }
        if (h == 0) out[OUT_IDX_OFF + t0 + et] = (float)B;
    }
#pragma unroll
    for (int off = 32; off > 0; off >>= 1)
        loss_t += __shfl_down(loss_t, off);
    if (lane == 0 && w < 2) atomicAdd(loss_sum, (double)loss_t);
}

__device__ __forceinline__ unsigned long long shfl_down_u64(unsigned long long v, int off) {
    unsigned int lo = (unsigned int)v, hi = (unsigned int)(v >> 32);
    lo = __shfl_down(lo, off);
    hi = __shfl_down(hi, off);
    return ((unsigned long long)hi << 32) | lo;
}

// ---------------------------------------------------------------------------
// Exact numpy-bitwise pass, v5 (r8): TPG 16 -> 8. Per-token arithmetic,
// staging content, packed-min reduce, finish writes bitwise-identical to
// verified v4 — only the token->group partition changes (halves the serial
// per-group chain; 2x active blocks, still << 256 CUs). ngroups <= 512
// guaranteed by FLAG_CAP=4096. f64 loss atomic order was already arbitrary.
// ---------------------------------------------------------------------------
__global__ __launch_bounds__(256) void vq_exact_min(
    const float* __restrict__ z, const float* __restrict__ cb,
    const float* __restrict__ bnorm,
    const unsigned int* __restrict__ flag_count,
    const int* __restrict__ flag_list,
    unsigned long long* __restrict__ packed_min,
    unsigned int* __restrict__ done_grp, unsigned int* __restrict__ done_all,
    float* __restrict__ out, double* __restrict__ loss_sum,
    unsigned int flag_cap) {
    __shared__ float zsh[TPG * 68];
    __shared__ float szs[TPG];
    __shared__ unsigned int s_old;

    const int tid = threadIdx.x;
    const int w = tid >> 6;
    const int lane = tid & 63;
    unsigned int count = *flag_count;
    if (count > flag_cap) count = flag_cap;
    const unsigned int ngroups = (count + TPG - 1) / TPG;   // <= 512

    if (count == 0) {   // no flagged tokens: block 0 writes the loss
        if (blockIdx.x == 0 && tid == 0) {
            double L = atomicAdd(loss_sum, 0.0);
            out[OUT_LOSS_OFF] = (float)(2.0 * L / (double)((size_t)TOKENS * DIM));
        }
        return;
    }

    const int q = blockIdx.x & 3;
    const unsigned int g = blockIdx.x >> 2;          // 0..511
    if (g >= ngroups) return;

    const int k = q * 256 + w * 64 + lane;           // this lane's code

    float row[DIM];
    {
        const float4* c4 = (const float4*)(cb + (size_t)k * DIM);
#pragma unroll
        for (int j = 0; j < 16; ++j) {
            float4 v = c4[j];
            row[4 * j + 0] = v.x; row[4 * j + 1] = v.y;
            row[4 * j + 2] = v.z; row[4 * j + 3] = v.w;
        }
    }
    const float bnk = bnorm[k];

    {
        const int i = tid >> 2, part = tid & 3;
        if (i < TPG) {
            const unsigned int li = g * TPG + i;
            if (li < count) {
                const int t = flag_list[li];
                const float4* zp = (const float4*)(z + (size_t)t * DIM + part * 16);
                float4* dst = (float4*)(zsh + i * 68 + part * 16);
#pragma unroll
                for (int e = 0; e < 4; ++e) dst[e] = zp[e];
            }
        }
    }
    __syncthreads();
    if (tid < TPG) szs[tid] = np_sumsq64(zsh + tid * 68);
    __syncthreads();

    for (int tt = 0; tt < TPG; ++tt) {
        const unsigned int li = g * TPG + tt;
        const float* zp = zsh + tt * 68;             // wave-uniform -> broadcast
        float l16[16];
#pragma unroll
        for (int g2 = 0; g2 < 4; ++g2) {
            float4 v0 = ((const float4*)(zp + 4 * g2))[0];
            float4 v1 = ((const float4*)(zp + 16 + 4 * g2))[0];
            float4 v2 = ((const float4*)(zp + 32 + 4 * g2))[0];
            float4 v3 = ((const float4*)(zp + 48 + 4 * g2))[0];
            float a0[4] = {v0.x, v0.y, v0.z, v0.w};
            float a1[4] = {v1.x, v1.y, v1.z, v1.w};
            float a2[4] = {v2.x, v2.y, v2.z, v2.w};
            float a3[4] = {v3.x, v3.y, v3.z, v3.w};
#pragma unroll
            for (int e = 0; e < 4; ++e) {
#pragma clang fp contract(off)
                int jj = 4 * g2 + e;
                float acc = a3[e] * row[48 + jj];
                acc = __fmaf_rn(a2[e], row[32 + jj], acc);
                acc = __fmaf_rn(a1[e], row[16 + jj], acc);
                acc = __fmaf_rn(a0[e], row[jj],      acc);
                l16[jj] = acc;
            }
        }
        float e_np;
        {
#pragma clang fp contract(off)
#pragma unroll
            for (int jj = 0; jj < 8; ++jj) l16[jj] = l16[jj] + l16[jj + 8];
#pragma unroll
            for (int jj = 0; jj < 4; ++jj) l16[jj] = l16[jj] + l16[jj + 4];
            l16[0] = l16[0] + l16[2];
            l16[1] = l16[1] + l16[3];
            e_np = l16[0] + l16[1];
        }
        float dd;
        {
#pragma clang fp contract(off)
            float t1 = szs[tt] + bnk;
            float mm = 2.0f * e_np;
            dd = t1 - mm;
        }
        unsigned long long pk =
            ((unsigned long long)__float_as_uint(dd) << 10) | (unsigned int)k;
#pragma unroll
        for (int off = 32; off > 0; off >>= 1) {
            unsigned long long o = shfl_down_u64(pk, off);
            pk = (o < pk) ? o : pk;
        }
        if (lane == 0 && li < count)
            atomicMin(&packed_min[li], pk);
    }

    // ---- fused finish: 4th quarter-block of this group writes outputs ----
    __threadfence();
    __syncthreads();
    if (tid == 0) s_old = atomicAdd(&done_grp[g], 1u);
    __syncthreads();
    if (s_old != 3u) return;
    __threadfence();

    for (int tt = w * (TPG / 4); tt < (w + 1) * (TPG / 4); ++tt) {
        const unsigned int li = g * TPG + tt;
        if (li >= count) break;
        const int t = flag_list[li];
        const unsigned long long pk = atomicAdd(&packed_min[li], 0ull);  // coherent
        const int best = (int)(pk & 1023ull);
        const float zl = zsh[tt * 68 + lane];
        const float zq = cb[(size_t)best * DIM + lane];
        float d, o;
        {
#pragma clang fp contract(off)
            d = zq - zl;
            o = zl + d;
        }
        out[(size_t)t * DIM + lane] = o;
        float l2 = d * d;
#pragma unroll
        for (int off = 32; off > 0; off >>= 1)
            l2 += __shfl_down(l2, off);
        if (lane == 0) {
            out[OUT_IDX_OFF + t] = (float)best;
            atomicAdd(loss_sum, (double)l2);
        }
    }

    __threadfence();
    __syncthreads();
    if (tid == 0) {
        unsigned int old = atomicAdd(done_all, 1u);
        if (old == ngroups - 1) {
            double L = atomicAdd(loss_sum, 0.0);   // coherent read-through
            out[OUT_LOSS_OFF] = (float)(2.0 * L / (double)((size_t)TOKENS * DIM));
        }
    }
}

extern "C" void kernel_launch(void* const* d_in, const int* in_sizes, int n_in,
                              void* d_out, int out_size, void* d_ws, size_t ws_size,
                              hipStream_t stream) {
    const float* z  = (const float*)d_in[0];   // [8,8192,64] f32
    const float* cb = (const float*)d_in[1];   // [1024,64] f32
    float* out = (float*)d_out;

    char* ws = (char*)d_ws;
    double* loss_sum = (double*)(ws + WS_LOSS);
    unsigned int* flag_count = (unsigned int*)(ws + WS_FLAGC);
    unsigned int* done_all = (unsigned int*)(ws + WS_DONEA);
    unsigned int* done_grp = (unsigned int*)(ws + WS_DGRP);
    float* bnorm = (float*)(ws + WS_BNORM);
    float* bns = (float*)(ws + WS_BNS);
    unsigned short* chi = (unsigned short*)(ws + WS_CHI);
    unsigned short* clo = (unsigned short*)(ws + WS_CLO);
    unsigned long long* packed = (unsigned long long*)(ws + WS_PACKED);
    int* flag_list = (int*)(ws + WS_FLAGS);

    unsigned int cap = 0;
    if (ws_size > WS_FLAGS + 4) {
        size_t c = (ws_size - WS_FLAGS) / 4;
        cap = (c > FLAG_CAP) ? FLAG_CAP : (unsigned int)c;
    }

    vq_prep<<<dim3(256), dim3(256), 0, stream>>>(
        cb, chi, clo, bnorm, bns, (unsigned int*)ws);
    vq_fast<<<dim3(TOKENS / 64), dim3(256), 0, stream>>>(
        z, cb, chi, clo, bns, out, flag_count, flag_list, packed, loss_sum, cap);
    vq_exact_min<<<dim3(2048), dim3(256), 0, stream>>>(
        z, cb, bnorm, flag_count, flag_list, packed, done_grp, done_all,
        out, loss_sum, cap);
}

// Round 9
// 136.731 us; speedup vs baseline: 1.0966x; 1.0121x over previous
//
#include <hip/hip_runtime.h>

#define TOKENS 65536
#define DIM 64
#define NCODE 1024
// fp16-screen margin (unscaled). Screen error bound: ~192 f32 roundings x
// ulp(3e5 scaled)/2^21 ~ 2.9e-6 worst-case; 1e-5 gives 3.4x headroom.
#define MARGIN 1e-5f
#define MARGINS (MARGIN * 2097152.0f)   // scaled-domain threshold (x 2^21)
#define FLAG_CAP 8192   // r9: block-per-token, no done_grp constraint

#define OUT_IDX_OFF ((size_t)TOKENS * DIM)          // 4194304
#define OUT_LOSS_OFF (OUT_IDX_OFF + TOKENS)         // 4259840

// ws layout (bytes):
#define WS_LOSS   0        // double
#define WS_FLAGC  8        // uint
#define WS_DONEA  12       // uint (global finisher counter)
#define WS_DGRP   16       // uint[512] (unused r9; still zeroed) -> 2064
#define WS_BNORM  2064     // f32[1024] -> 6160 (unscaled, exact pass)
#define WS_BNS    6160     // f32[1024] -> 10256 (x2^21, screen)
#define WS_CHI    10256    // ushort[65536] -> 141328 (fp16 hi of -8192*c)
#define WS_CLO    141328   // ushort[65536] -> 272400 (fp16 lo)
#define WS_PACKED 272400   // u64[8192] -> 337936 (unused r9, kept for layout)
#define WS_FLAGS  337936   // int[8192] -> 370704

typedef __attribute__((ext_vector_type(8))) short short8;
typedef __attribute__((ext_vector_type(8))) _Float16 half8;
typedef __attribute__((ext_vector_type(4))) float f32x4;

static __device__ __forceinline__ half8 as_h8(short8 v) {
    return __builtin_bit_cast(half8, v);
}

// ---------------------------------------------------------------------------
// numpy-bitwise f32 sum-of-squares — VERIFIED absmax=0 (round 2). Do not touch.
// ---------------------------------------------------------------------------
__device__ __forceinline__ float np_sumsq64(const float* __restrict__ x) {
#pragma clang fp contract(off)
    float r[8];
#pragma unroll
    for (int j = 0; j < 8; ++j) r[j] = x[j] * x[j];
#pragma unroll
    for (int i = 8; i < 64; i += 8) {
#pragma unroll
        for (int j = 0; j < 8; ++j) {
            float sq = x[i + j] * x[i + j];
            r[j] = r[j] + sq;
        }
    }
    return ((r[0] + r[1]) + (r[2] + r[3])) + ((r[4] + r[5]) + (r[6] + r[7]));
}

// ---------------------------------------------------------------------------
// Prep v2 (r13, UNCHANGED): codebook -> fp16 hi/lo A-frags of (-2*4096*C)
// + bnorm (unscaled, exact pass) + bns (= bnorm * 2^21, screen).
// ---------------------------------------------------------------------------
__global__ __launch_bounds__(256) void vq_prep(
    const float* __restrict__ cb, unsigned short* __restrict__ chi,
    unsigned short* __restrict__ clo, float* __restrict__ bnorm,
    float* __restrict__ bns,
    unsigned int* __restrict__ ctrl /* 516 u32 at ws+0 */) {
    int tid = blockIdx.x * 256 + threadIdx.x;   // 0..65535
    if (tid < 516) ctrl[tid] = 0u;
    int j = tid & 7;
    int L = (tid >> 3) & 63;
    int cs = tid >> 9;          // 0..127
    int s = cs & 1, c = cs >> 1;
    int code = c * 16 + (L & 15);
    int d = s * 32 + (L >> 4) * 8 + j;
    float v = -8192.0f * cb[(size_t)code * DIM + d];   // -2c * 4096 (exact)
    _Float16 h = (_Float16)v;                          // RN f32->f16
    float hf = (float)h;
    float lo;
    {
#pragma clang fp contract(off)
        lo = v - hf;                                   // exact in f32
    }
    _Float16 l = (_Float16)lo;
    chi[tid] = __builtin_bit_cast(unsigned short, h);
    clo[tid] = __builtin_bit_cast(unsigned short, l);

    if (tid < NCODE) {
        float bn = np_sumsq64(cb + (size_t)tid * DIM);
        bnorm[tid] = bn;
        bns[tid] = bn * 2097152.0f;                    // x 2^21 (exact)
    }
}

__device__ __forceinline__ void top2_merge(float& a1, float& a2, int& ai,
                                           float b1, float b2, int bi) {
    float n1 = fminf(a1, b1);
    float n2 = fminf(fmaxf(a1, b1), fminf(a2, b2));
    ai = (b1 < a1) ? bi : ai;   // ties keep a (exact ties get flagged anyway)
    a1 = n1; a2 = n2;
}

// ---------------------------------------------------------------------------
// Fast screen, v9 (r13/r3 VERBATIM — best verified: 51.5us). r4 (code-split),
// r5 (wide block), r7 (global_load_lds DMA) all regressed; r7 post-mortem:
// DMA's LDS writes land during compute and contend with ds_reads on the LDS
// pipe, vs reg-staging's end-of-group burst that overlaps other blocks'
// compute. Do not restructure without new counter evidence.
// ---------------------------------------------------------------------------
__global__ __launch_bounds__(256, 4) void vq_fast(
    const float* __restrict__ z, const float* __restrict__ cb,
    const unsigned short* __restrict__ cfrag_hi,
    const unsigned short* __restrict__ cfrag_lo,
    const float* __restrict__ bnorm_s, float* __restrict__ out,
    unsigned int* __restrict__ flag_count, int* __restrict__ flag_list,
    unsigned long long* __restrict__ packed_min,
    double* __restrict__ loss_sum, unsigned int flag_cap) {
    __shared__ short8 sh_hi[2][512];   // [buf][(cc*2+step)*64 + lane], 8KB each
    __shared__ short8 sh_lo[2][512];
    __shared__ float bn_lds[NCODE];
    __shared__ int s_best[64];
    __shared__ int s_flag[64];

    const int tid = threadIdx.x;
    const int lane = tid & 63;
    const int w = tid >> 6;
    const int t0 = blockIdx.x * 64;
    const int tw = t0 + w * 16;              // this wave's 16 tokens
    const int col = lane & 15;
    const int quad = lane >> 4;

    // stage scaled bnorm into LDS (4 KB)
    ((float4*)bn_lds)[tid] = ((const float4*)bnorm_s)[tid];

    // token B-fragments (fp16 hi/lo of z*512), 2 K-steps, in registers
    half8 zhi[2], zlo[2];
#pragma unroll
    for (int s = 0; s < 2; ++s) {
        const float* zp = z + (size_t)(tw + col) * DIM + s * 32 + quad * 8;
        float4 f0 = ((const float4*)zp)[0];
        float4 f1 = ((const float4*)zp)[1];
        float f[8] = {f0.x, f0.y, f0.z, f0.w, f1.x, f1.y, f1.z, f1.w};
        half8 hh8, ll8;
#pragma unroll
        for (int j = 0; j < 8; ++j) {
            float sv = f[j] * 512.0f;        // exact pow2 scale
            _Float16 hh = (_Float16)sv;      // RN
            float hf = (float)hh;
            float lo;
            {
#pragma clang fp contract(off)
                lo = sv - hf;                // exact in f32
            }
            hh8[j] = hh;
            ll8[j] = (_Float16)lo;
        }
        zhi[s] = hh8; zlo[s] = ll8;
    }

    const short8* CH = (const short8*)cfrag_hi;   // 4096 short8 (64 chunks)
    const short8* CL = (const short8*)cfrag_lo;

    // stage group 0 (4 chunks = 512 short8 per array; 2 per thread per array)
    {
        short8 a0 = CH[tid], a1 = CH[tid + 256];
        short8 b0 = CL[tid], b1 = CL[tid + 256];
        sh_hi[0][tid] = a0; sh_hi[0][tid + 256] = a1;
        sh_lo[0][tid] = b0; sh_lo[0][tid + 256] = b1;
    }
    __syncthreads();

    float m1 = 3.0e38f, m2 = 3.0e38f;
    int bi = 0;
    const int koff = quad * 4;

    for (int g = 0; g < 16; ++g) {
        const int buf = g & 1;
        short8 a0, a1, b0, b1;
        if (g < 15) {               // issue next group's loads first
            const int base = (g + 1) * 512 + tid;
            a0 = CH[base]; a1 = CH[base + 256];
            b0 = CL[base]; b1 = CL[base + 256];
        }
#pragma unroll
        for (int cc = 0; cc < 4; ++cc) {
            const int c = g * 4 + cc;
            short8 ch0 = sh_hi[buf][(cc * 2 + 0) * 64 + lane];
            short8 ch1 = sh_hi[buf][(cc * 2 + 1) * 64 + lane];
            short8 cl0 = sh_lo[buf][(cc * 2 + 0) * 64 + lane];
            short8 cl1 = sh_lo[buf][(cc * 2 + 1) * 64 + lane];
            const int cbase = c * 16 + koff;
            const f32x4 bn = *(const f32x4*)&bn_lds[cbase];
            f32x4 acc = bn;
            acc = __builtin_amdgcn_mfma_f32_16x16x32_f16(as_h8(ch0), zhi[0], acc, 0, 0, 0);
            acc = __builtin_amdgcn_mfma_f32_16x16x32_f16(as_h8(cl0), zhi[0], acc, 0, 0, 0);
            acc = __builtin_amdgcn_mfma_f32_16x16x32_f16(as_h8(ch0), zlo[0], acc, 0, 0, 0);
            acc = __builtin_amdgcn_mfma_f32_16x16x32_f16(as_h8(ch1), zhi[1], acc, 0, 0, 0);
            acc = __builtin_amdgcn_mfma_f32_16x16x32_f16(as_h8(cl1), zhi[1], acc, 0, 0, 0);
            acc = __builtin_amdgcn_mfma_f32_16x16x32_f16(as_h8(ch1), zlo[1], acc, 0, 0, 0);
#pragma unroll
            for (int i = 0; i < 4; ++i) {
                float u = acc[i];
                float om1 = m1;
                bool lt = u < om1;
                float fm = fminf(m2, u);
                m2 = lt ? om1 : fm;
                m1 = lt ? u : om1;
                bi = lt ? (cbase + i) : bi;
            }
        }
        if (g < 15) {
            sh_hi[buf ^ 1][tid] = a0; sh_hi[buf ^ 1][tid + 256] = a1;
            sh_lo[buf ^ 1][tid] = b0; sh_lo[buf ^ 1][tid + 256] = b1;
            __syncthreads();
        }
    }

    // in-wave quad merge (lanes l, l^16, l^32, l^48 share a token column)
    {
        float a1 = m1, a2 = m2;
        int ai = bi;
        {
            float o1 = __shfl_xor(a1, 16); float o2 = __shfl_xor(a2, 16);
            int oi = __shfl_xor(ai, 16);
            top2_merge(a1, a2, ai, o1, o2, oi);
        }
        {
            float o1 = __shfl_xor(a1, 32); float o2 = __shfl_xor(a2, 32);
            int oi = __shfl_xor(ai, 32);
            top2_merge(a1, a2, ai, o1, o2, oi);
        }
        if (quad == 0) {
            const int slot = w * 16 + col;
            int fl = (a2 - a1) < MARGINS;
            if (fl) {
                unsigned int pos = atomicAdd(flag_count, 1u);
                if (pos >= flag_cap) fl = 0;
                else {
                    flag_list[pos] = t0 + slot;
                    packed_min[pos] = ~0ull;   // harmless (unused r9)
                }
            }
            s_best[slot] = ai;
            s_flag[slot] = fl;
        }
    }
    __syncthreads();

    // epilogue: 2 threads per token, 32 floats each (r6-verified partial
    // structure); flagged deferred.
    const int et = tid >> 1, h = tid & 1;
    float loss_t = 0.0f;
    if (et < 64 && !s_flag[et]) {
        const int B = s_best[et];
        const float4* cq  = (const float4*)(cb + (size_t)B * DIM + h * 32);
        const float4* zq4 = (const float4*)(z + (size_t)(t0 + et) * DIM + h * 32);
        float4* o4 = (float4*)(out + (size_t)(t0 + et) * DIM + h * 32);
#pragma unroll
        for (int jj = 0; jj < 8; ++jj) {
#pragma clang fp contract(off)
            float4 cc = cq[jj];
            float4 zz = zq4[jj];
            float d0 = cc.x - zz.x, d1 = cc.y - zz.y;
            float d2 = cc.z - zz.z, d3 = cc.w - zz.w;
            float4 o;
            o.x = zz.x + d0; o.y = zz.y + d1;
            o.z = zz.z + d2; o.w = zz.w + d3;
            o4[jj] = o;
            loss_t = __fmaf_rn(d0, d0, loss_t);
            loss_t = __fmaf_rn(d1, d1, loss_t);
            loss_t = __fmaf_rn(d2, d2, loss_t);
            loss_t = __fmaf_rn(d3, d3, loss_t);
        }
        if (h == 0) out[OUT_IDX_OFF + t0 + et] = (float)B;
    }
#pragma unroll
    for (int off = 32; off > 0; off >>= 1)
        loss_t += __shfl_down(loss_t, off);
    if (lane == 0 && w < 2) atomicAdd(loss_sum, (double)loss_t);
}

__device__ __forceinline__ unsigned long long shfl_down_u64(unsigned long long v, int off) {
    unsigned int lo = (unsigned int)v, hi = (unsigned int)(v >> 32);
    lo = __shfl_down(lo, off);
    hi = __shfl_down(hi, off);
    return ((unsigned long long)hi << 32) | lo;
}

// ---------------------------------------------------------------------------
// Exact numpy-bitwise pass, v6 (r9): ONE BLOCK PER FLAGGED TOKEN. Removes
// the serial token chain (r8: halving it 16->8 bought ~9us of 'other'),
// packed_min atomics, and the done_grp 4-quarter rendezvous. Each thread
// handles codes {tid, 256+tid, 512+tid, 768+tid}; per-(token,code)
// arithmetic is copied VERBATIM from verified v4 (same input bits -> same
// dd bits); packed u64 min over the block (wave butterfly + 4-slot LDS
// merge) is order-invariant -> identical argmin/tie result. Finish ops
// (d, o, l2 butterfly, idx/loss writes) identical to v4's fused finish.
// done_all orders the final loss write; count==0 handled by block 0.
// ---------------------------------------------------------------------------
__global__ __launch_bounds__(256) void vq_exact_min(
    const float* __restrict__ z, const float* __restrict__ cb,
    const float* __restrict__ bnorm,
    const unsigned int* __restrict__ flag_count,
    const int* __restrict__ flag_list,
    unsigned long long* __restrict__ packed_min /* unused */,
    unsigned int* __restrict__ done_grp /* unused */,
    unsigned int* __restrict__ done_all,
    float* __restrict__ out, double* __restrict__ loss_sum,
    unsigned int flag_cap) {
    __shared__ float zsh[68];
    __shared__ float s_zs;
    __shared__ unsigned long long s_pk[4];
    __shared__ unsigned long long s_min;

    const int tid = threadIdx.x;
    const int w = tid >> 6;
    const int lane = tid & 63;
    unsigned int count = *flag_count;
    if (count > flag_cap) count = flag_cap;

    if (count == 0) {   // no flagged tokens: block 0 writes the loss
        if (blockIdx.x == 0 && tid == 0) {
            double L = atomicAdd(loss_sum, 0.0);
            out[OUT_LOSS_OFF] = (float)(2.0 * L / (double)((size_t)TOKENS * DIM));
        }
        return;
    }
    if (blockIdx.x >= count) return;

    const int t = flag_list[blockIdx.x];

    // stage token (float4 copy, content-identical to v4 staging)
    if (tid < 4) {
        const float4* zp = (const float4*)(z + (size_t)t * DIM + tid * 16);
        float4* dst = (float4*)(zsh + tid * 16);
#pragma unroll
        for (int e = 0; e < 4; ++e) dst[e] = zp[e];
    }
    __syncthreads();
    if (tid == 0) s_zs = np_sumsq64(zsh);
    __syncthreads();

    const float szs = s_zs;
    const float* zp = zsh;
    unsigned long long pk = ~0ull;

    for (int e = 0; e < 4; ++e) {
        const int k = e * 256 + tid;              // code index
        float row[DIM];
        {
            const float4* c4 = (const float4*)(cb + (size_t)k * DIM);
#pragma unroll
            for (int j = 0; j < 16; ++j) {
                float4 v = c4[j];
                row[4 * j + 0] = v.x; row[4 * j + 1] = v.y;
                row[4 * j + 2] = v.z; row[4 * j + 3] = v.w;
            }
        }
        const float bnk = bnorm[k];

        float l16[16];
#pragma unroll
        for (int g2 = 0; g2 < 4; ++g2) {
            float4 v0 = ((const float4*)(zp + 4 * g2))[0];
            float4 v1 = ((const float4*)(zp + 16 + 4 * g2))[0];
            float4 v2 = ((const float4*)(zp + 32 + 4 * g2))[0];
            float4 v3 = ((const float4*)(zp + 48 + 4 * g2))[0];
            float a0[4] = {v0.x, v0.y, v0.z, v0.w};
            float a1[4] = {v1.x, v1.y, v1.z, v1.w};
            float a2[4] = {v2.x, v2.y, v2.z, v2.w};
            float a3[4] = {v3.x, v3.y, v3.z, v3.w};
#pragma unroll
            for (int ee = 0; ee < 4; ++ee) {
#pragma clang fp contract(off)
                int jj = 4 * g2 + ee;
                float acc = a3[ee] * row[48 + jj];
                acc = __fmaf_rn(a2[ee], row[32 + jj], acc);
                acc = __fmaf_rn(a1[ee], row[16 + jj], acc);
                acc = __fmaf_rn(a0[ee], row[jj],      acc);
                l16[jj] = acc;
            }
        }
        float e_np;
        {
#pragma clang fp contract(off)
#pragma unroll
            for (int jj = 0; jj < 8; ++jj) l16[jj] = l16[jj] + l16[jj + 8];
#pragma unroll
            for (int jj = 0; jj < 4; ++jj) l16[jj] = l16[jj] + l16[jj + 4];
            l16[0] = l16[0] + l16[2];
            l16[1] = l16[1] + l16[3];
            e_np = l16[0] + l16[1];
        }
        float dd;
        {
#pragma clang fp contract(off)
            float t1 = szs + bnk;
            float mm = 2.0f * e_np;
            dd = t1 - mm;
        }
        unsigned long long p =
            ((unsigned long long)__float_as_uint(dd) << 10) | (unsigned int)k;
        pk = (p < pk) ? p : pk;
    }

    // block-wide u64 min: wave butterfly then 4-slot LDS merge
#pragma unroll
    for (int off = 32; off > 0; off >>= 1) {
        unsigned long long o = shfl_down_u64(pk, off);
        pk = (o < pk) ? o : pk;
    }
    if (lane == 0) s_pk[w] = pk;
    __syncthreads();
    if (tid == 0) {
        unsigned long long m = s_pk[0];
        m = (s_pk[1] < m) ? s_pk[1] : m;
        m = (s_pk[2] < m) ? s_pk[2] : m;
        m = (s_pk[3] < m) ? s_pk[3] : m;
        s_min = m;
    }
    __syncthreads();

    // finish (ops identical to v4's fused finish), wave 0 only
    if (w == 0) {
        const int best = (int)(s_min & 1023ull);
        const float zl = zsh[lane];
        const float zq = cb[(size_t)best * DIM + lane];
        float d, o;
        {
#pragma clang fp contract(off)
            d = zq - zl;
            o = zl + d;
        }
        out[(size_t)t * DIM + lane] = o;
        float l2 = d * d;
#pragma unroll
        for (int off = 32; off > 0; off >>= 1)
            l2 += __shfl_down(l2, off);
        if (lane == 0) {
            out[OUT_IDX_OFF + t] = (float)best;
            atomicAdd(loss_sum, (double)l2);
        }
    }

    __threadfence();
    __syncthreads();
    if (tid == 0) {
        unsigned int old = atomicAdd(done_all, 1u);
        if (old == count - 1) {
            double L = atomicAdd(loss_sum, 0.0);   // coherent read-through
            out[OUT_LOSS_OFF] = (float)(2.0 * L / (double)((size_t)TOKENS * DIM));
        }
    }
}

extern "C" void kernel_launch(void* const* d_in, const int* in_sizes, int n_in,
                              void* d_out, int out_size, void* d_ws, size_t ws_size,
                              hipStream_t stream) {
    const float* z  = (const float*)d_in[0];   // [8,8192,64] f32
    const float* cb = (const float*)d_in[1];   // [1024,64] f32
    float* out = (float*)d_out;

    char* ws = (char*)d_ws;
    double* loss_sum = (double*)(ws + WS_LOSS);
    unsigned int* flag_count = (unsigned int*)(ws + WS_FLAGC);
    unsigned int* done_all = (unsigned int*)(ws + WS_DONEA);
    unsigned int* done_grp = (unsigned int*)(ws + WS_DGRP);
    float* bnorm = (float*)(ws + WS_BNORM);
    float* bns = (float*)(ws + WS_BNS);
    unsigned short* chi = (unsigned short*)(ws + WS_CHI);
    unsigned short* clo = (unsigned short*)(ws + WS_CLO);
    unsigned long long* packed = (unsigned long long*)(ws + WS_PACKED);
    int* flag_list = (int*)(ws + WS_FLAGS);

    unsigned int cap = 0;
    if (ws_size > WS_FLAGS + 4) {
        size_t c = (ws_size - WS_FLAGS) / 4;
        cap = (c > FLAG_CAP) ? FLAG_CAP : (unsigned int)c;
    }

    vq_prep<<<dim3(256), dim3(256), 0, stream>>>(
        cb, chi, clo, bnorm, bns, (unsigned int*)ws);
    vq_fast<<<dim3(TOKENS / 64), dim3(256), 0, stream>>>(
        z, cb, chi, clo, bns, out, flag_count, flag_list, packed, loss_sum, cap);
    vq_exact_min<<<dim3(FLAG_CAP), dim3(256), 0, stream>>>(
        z, cb, bnorm, flag_count, flag_list, packed, done_grp, done_all,
        out, loss_sum, cap);
}